// Round 5
// baseline (119.600 us; speedup 1.0000x reference)
//
#include <hip/hip_runtime.h>
#include <math.h>

// Problem constants (fixed by the harness's setup_inputs()).
#define NN      20000
#define IN_DIM  256
#define HID_DIM 256
#define OUT_DIM 128
#define EE      320000
#define GG      64

#define HQB 313   // hist blocks (1024 thr): 313*1024 >= EE
#define CHB 16    // replicated q-chain blocks: block cb writes q1[16cb..16cb+16)
#define MVB 1250  // matvec blocks in D2: 1250 * 16 waves = 20000 rows
#define SB  1250  // scatter blocks: 1250*256 == EE exactly
#define GB  313   // gather blocks: 313*256 >= NN*4

// ---------------------------------------------------------------------------
// Affine collapse (network has no activations):
//   q4 = W4^T lw; q3 = W3^T q4; q2 = W2^T q3; q1 = W1^T q2   (256-vectors)
//   d1 = b1.q2; d2 = b2.q3; d3 = b3.q4; c4 = b4.lw           (scalars)
//   u0 = x.q1;  u_i[c] = sum_{e:col=c} norm_e*(u_{i-1}[row_e] + d_i)
//   out[g] = pool(u4)/maxcnt + lb
//
// Round-14: rocprof says round-13's single-block q-chain = 45us (one CU
// streaming 900KB cold W from HBM at ~25GB/s). Fix: 16 REPLICATED chain
// blocks -- each runs the full 4-gemv chain (W reads shared via L2/L3,
// cold misses amortized across 16 CUs), block cb writes only its 16-wide
// q1 slice, block 0 adds the bias dots. No inter-block sync needed; the
// only cross-stage dependency (the 1KB q vector) is block-local.
// Scatter/gather/pool numerics stay verbatim (proven absmax=0.0).
// 8 dispatches: memset, hist∥chain, scan∥cnt∥matvec, scatter, g x3, final.
// ---------------------------------------------------------------------------

__device__ __forceinline__ float ldf_mall(const float* p) {
  return __hip_atomic_load(p, __ATOMIC_RELAXED, __HIP_MEMORY_SCOPE_AGENT);
}

// D1: blocks [0,313) edge histograms; blocks [313,329) replicated q-chain.
__global__ __launch_bounds__(1024) void k_hist_qchain(
    const int* __restrict__ erow, const int* __restrict__ ecol,
    int* __restrict__ deg, int* __restrict__ ccnt,
    const float* __restrict__ W1, const float* __restrict__ b1,
    const float* __restrict__ W2, const float* __restrict__ b2,
    const float* __restrict__ W3, const float* __restrict__ b3,
    const float* __restrict__ W4, const float* __restrict__ b4,
    const float* __restrict__ lw, float* __restrict__ q1g,
    float* __restrict__ dv) {
  const int bid = blockIdx.x, tid = threadIdx.x;

  if (bid < HQB) {
    int e = bid * 1024 + tid;
    if (e < EE) {
      atomicAdd(&deg[erow[e]], 1);
      atomicAdd(&ccnt[ecol[e]], 1);
    }
    return;
  }

  // ---- replicated q-chain block cb ∈ [0,16) ----
  const int cb = bid - HQB;
  __shared__ float lws[128];
  __shared__ float qa[256], qb[256], qc[256], qd[256];  // q4,q3,q2,q1
  __shared__ float part[4][256];
  __shared__ float red[16];
  const int j = tid & 255, tq = tid >> 8;

  if (tid < 128) lws[tid] = lw[tid];
  __syncthreads();

  // qout[j] = sum_{t<K} W[t*256+j] * qin[t]; 4-way K-split, coalesced
  // across j (each t-row is a contiguous 1KB read by 256 threads).
  auto gemv = [&](const float* W, const float* qin, float* qout, int K) {
    const int quarter = K >> 2, t0 = tq * quarter;
    float s = 0.f;
#pragma unroll 4
    for (int m = 0; m < quarter; ++m) {
      int t = t0 + m;
      s += W[(size_t)t * 256 + j] * qin[t];
    }
    part[tq][j] = s;
    __syncthreads();
    if (tq == 0) qout[j] = part[0][j] + part[1][j] + part[2][j] + part[3][j];
    __syncthreads();
  };

  gemv(W4, lws, qa, OUT_DIM);   // q4 = W4^T lw   (K = 128)
  gemv(W3, qa, qb, HID_DIM);    // q3
  gemv(W2, qb, qc, HID_DIM);    // q2
  gemv(W1, qc, qd, HID_DIM);    // q1
  if (tid < 16) q1g[cb * 16 + tid] = qd[cb * 16 + tid];

  if (cb == 0) {
    auto dot = [&](const float* a, const float* bl, int K, float* dst) {
      float p = (tid < K) ? a[tid] * bl[tid] : 0.f;
#pragma unroll
      for (int off = 32; off; off >>= 1) p += __shfl_down(p, off);
      if ((tid & 63) == 0) red[tid >> 6] = p;
      __syncthreads();
      if (tid == 0) { float s = 0.f; for (int k = 0; k < 16; ++k) s += red[k]; *dst = s; }
      __syncthreads();
    };
    dot(b1, qc, HID_DIM, &dv[0]);
    dot(b2, qb, HID_DIM, &dv[1]);
    dot(b3, qa, HID_DIM, &dv[2]);
    dot(b4, lws, OUT_DIM, &dv[3]);
  }
}

// D2: block 0 = exclusive scan of ccnt -> cstart/cursor; block 1 = per-graph
// node counts; blocks 2..1251 = u0 = x.q1 (one wave per row, float4 lanes).
__global__ __launch_bounds__(1024) void k_scan_cnt_mv(
    const int* __restrict__ ccnt, int* __restrict__ cstart, int* __restrict__ cursor,
    const int* __restrict__ batch, float* __restrict__ outcnt,
    const float* __restrict__ x, const float* __restrict__ q1,
    float* __restrict__ u0) {
  int bid = blockIdx.x, tid = threadIdx.x, lane = tid & 63, wid = tid >> 6;

  if (bid == 0) {  // exclusive scan (verbatim proven code)
    __shared__ int ws[16];
    const int PER = 20;            // 1024*20 = 20480 >= NN
    int base = tid * PER;
    int v[PER]; int sum = 0;
#pragma unroll
    for (int i = 0; i < PER; ++i) { int idx = base + i; v[i] = (idx < NN) ? ccnt[idx] : 0; sum += v[i]; }
    int incl = sum;
#pragma unroll
    for (int off = 1; off < 64; off <<= 1) { int t = __shfl_up(incl, off); if (lane >= off) incl += t; }
    if (lane == 63) ws[wid] = incl;
    __syncthreads();
    if (tid == 0) { int r = 0; for (int j = 0; j < 16; ++j) { int t = ws[j]; ws[j] = r; r += t; } }
    __syncthreads();
    int run = ws[wid] + incl - sum;
#pragma unroll
    for (int i = 0; i < PER; ++i) {
      int idx = base + i;
      if (idx < NN) { cstart[idx] = run; cursor[idx] = run; }
      run += v[i];
    }
    if (tid == 1023) cstart[NN] = run;   // == EE
    return;
  }

  if (bid == 1) {  // per-graph node counts (verbatim proven code)
    for (int base = 0; base < NN; base += 1024) {
      int n = base + tid;
      int b = -1; float cn = 0.f;
      if (n < NN) { b = batch[n]; cn = 1.f; }
#pragma unroll
      for (int off = 1; off < 64; off <<= 1) {
        float c2 = __shfl_up(cn, off);
        int   b2 = __shfl_up(b, off);
        if (lane >= off && b2 == b) cn += c2;
      }
      int bn = __shfl_down(b, 1);
      if (((lane == 63) || (bn != b)) && b >= 0) atomicAdd(&outcnt[b], cn);
    }
    return;
  }

  // matvec: wave w of block handles row (bid-2)*16 + w.
  int r = (bid - 2) * 16 + wid;
  if (r >= NN) return;
  const float4 xv = *(const float4*)(x + (size_t)r * IN_DIM + lane * 4);
  const float4 qv = *(const float4*)(q1 + lane * 4);
  float s = xv.x * qv.x + xv.y * qv.y + xv.z * qv.z + xv.w * qv.w;
#pragma unroll
  for (int off = 32; off; off >>= 1) s += __shfl_down(s, off);
  if (lane == 0) u0[r] = s;
}

// D3: counting-sort CSR scatter (fused norm), int2-packed {row, val}.
__global__ __launch_bounds__(256) void k_scatter(
    const int* __restrict__ erow, const int* __restrict__ ecol,
    const int* __restrict__ deg, int* __restrict__ cursor,
    int2* __restrict__ sedge) {
  int e = blockIdx.x * 256 + threadIdx.x;   // grid = 1250, exact
  int r = erow[e], c = ecol[e];
  int slot = atomicAdd(&cursor[c], 1);
  float dr = (float)deg[r], dc = (float)deg[c];
  float val = (1.0f / sqrtf(dr)) * (1.0f / sqrtf(dc));  // deg==0 -> inf, as ref
  sedge[slot] = make_int2(r, __float_as_int(val));
}

// D4-D6: atomic-free A-application, 4 lanes per node (proven verbatim).
__global__ __launch_bounds__(256) void k_gather(
    const int* __restrict__ cstart, const int2* __restrict__ sedge,
    const float* __restrict__ uin, const float* __restrict__ dptr,
    float* __restrict__ uout) {
  int gid = blockIdx.x * 256 + threadIdx.x;
  int n = gid >> 2, l = gid & 3;
  if (n >= NN) return;
  int s0 = cstart[n], s1 = cstart[n + 1];
  float acc = 0.f, es = 0.f;
  for (int s = s0 + l; s < s1; s += 4) {
    int2 ev = sedge[s];
    float v = __int_as_float(ev.y);
    acc += v * uin[ev.x];
    es  += v;
  }
  acc += __shfl_xor(acc, 1); es += __shfl_xor(es, 1);
  acc += __shfl_xor(acc, 2); es += __shfl_xor(es, 2);
  if (l == 0) uout[n] = acc + dptr[0] * es;
}

// D7: last A-application + segmented per-node pool + last-block finalize.
__global__ __launch_bounds__(256) void k_gather_pool_final(
    const int* __restrict__ cstart, const int2* __restrict__ sedge,
    const float* __restrict__ uin, const float* __restrict__ dptr,
    const int* __restrict__ batch, float* __restrict__ outsum,
    const float* __restrict__ outcnt, const float* __restrict__ lb,
    float* __restrict__ out, int* __restrict__ done, int nblocks) {
  int gid = blockIdx.x * 256 + threadIdx.x;
  int lane = threadIdx.x & 63;
  int n = gid >> 2, l = gid & 3;
  float pv = 0.f; int b = -1;
  if (n < NN) {
    int s0 = cstart[n], s1 = cstart[n + 1];
    float acc = 0.f, es = 0.f;
    for (int s = s0 + l; s < s1; s += 4) {
      int2 ev = sedge[s];
      float v = __int_as_float(ev.y);
      acc += v * uin[ev.x];
      es  += v;
    }
    acc += __shfl_xor(acc, 1); es += __shfl_xor(es, 1);
    acc += __shfl_xor(acc, 2); es += __shfl_xor(es, 2);
    b = batch[n];
    if (l == 0) pv = acc + dptr[0] * es;   // node total on lane l==0 only
  }
#pragma unroll
  for (int off = 1; off < 64; off <<= 1) {
    float s2 = __shfl_up(pv, off);
    int   b2 = __shfl_up(b, off);
    if (lane >= off && b2 == b) pv += s2;
  }
  int bn = __shfl_down(b, 1);
  if (((lane == 63) || (bn != b)) && b >= 0) atomicAdd(&outsum[b], pv);

  // __syncthreads drains this block's vmem (outsum atomics complete at MALL)
  // before thread 0 signals; the LAST block to signal finalizes, reading
  // outsum/outcnt through MALL-coherent loads (proven pattern).
  __syncthreads();
  __shared__ int winner;
  if (threadIdx.x == 0) {
    int old = __hip_atomic_fetch_add(done, 1, __ATOMIC_RELAXED, __HIP_MEMORY_SCOPE_AGENT);
    winner = (old == nblocks - 1) ? 1 : 0;
  }
  __syncthreads();
  if (winner && threadIdx.x < GG) {
    int g = threadIdx.x;
    float m = ldf_mall(&outcnt[g]);
#pragma unroll
    for (int off = 32; off; off >>= 1) m = fmaxf(m, __shfl_xor(m, off));
    out[g] = ldf_mall(&outsum[g]) / m + lb[0];
  }
}

extern "C" void kernel_launch(void* const* d_in, const int* in_sizes, int n_in,
                              void* d_out, int out_size, void* d_ws, size_t ws_size,
                              hipStream_t stream) {
  (void)in_sizes; (void)n_in; (void)out_size; (void)ws_size;
  const float* x     = (const float*)d_in[0];
  const int*   erow  = (const int*)d_in[1];          // edge_index[0,:]
  const int*   ecol  = ((const int*)d_in[1]) + EE;   // edge_index[1,:]
  const int*   batch = (const int*)d_in[2];
  const float* W1 = (const float*)d_in[4];
  const float* b1 = (const float*)d_in[5];
  const float* W2 = (const float*)d_in[6];
  const float* b2 = (const float*)d_in[7];
  const float* W3 = (const float*)d_in[8];
  const float* b3 = (const float*)d_in[9];
  const float* W4 = (const float*)d_in[10];
  const float* b4 = (const float*)d_in[11];
  const float* lw = (const float*)d_in[12];
  const float* lb = (const float*)d_in[13];
  float* out = (float*)d_out;

  // Workspace layout (256-byte aligned slots).
  const size_t PN = 80128;  // 20000*4 rounded up to 256
  char* w = (char*)d_ws;
  // --- memset zone ---
  int*   deg    = (int*)w;    w += PN;
  int*   ccnt   = (int*)w;    w += PN;
  float* outsum = (float*)w;  w += 256;
  float* outcnt = (float*)w;  w += 256;
  int*   done   = (int*)w;    w += 256;
  size_t zbytes = (size_t)(w - (char*)d_ws);
  // --- fully-overwritten scratch ---
  int*   cstart = (int*)w;    w += PN + 256;          // NN+1 entries
  int*   cursor = (int*)w;    w += PN;
  int2*  sedge  = (int2*)w;   w += (size_t)EE * 8;    // packed {row, norm}
  float* q1     = (float*)w;  w += 1024;
  float* dv     = (float*)w;  w += 256;
  float* u0     = (float*)w;  w += PN;
  float* u1     = (float*)w;  w += PN;
  float* u2     = (float*)w;  w += PN;
  float* u3     = (float*)w;  w += PN;

  // D0: zero accumulators (stream-ordered, graph-capture-safe).
  hipMemsetAsync(d_ws, 0, zbytes, stream);
  // D1: edge histograms ∥ replicated q-chain + bias dots.
  k_hist_qchain<<<HQB + CHB, 1024, 0, stream>>>(erow, ecol, deg, ccnt,
                                                W1, b1, W2, b2, W3, b3, W4, b4,
                                                lw, q1, dv);
  // D2: scan ∥ graph counts ∥ u0 = x.q1.
  k_scan_cnt_mv<<<2 + MVB, 1024, 0, stream>>>(ccnt, cstart, cursor, batch,
                                              outcnt, x, q1, u0);
  // D3: CSR counting-sort scatter.
  k_scatter<<<SB, 256, 0, stream>>>(erow, ecol, deg, cursor, sedge);
  // D4-D6: three A-applications.
  k_gather<<<GB, 256, 0, stream>>>(cstart, sedge, u0, dv + 0, u1);
  k_gather<<<GB, 256, 0, stream>>>(cstart, sedge, u1, dv + 1, u2);
  k_gather<<<GB, 256, 0, stream>>>(cstart, sedge, u2, dv + 2, u3);
  // D7: last application + per-node pool + last-block finalize.
  k_gather_pool_final<<<GB, 256, 0, stream>>>(cstart, sedge, u3, dv + 3, batch,
                                              outsum, outcnt, lb, out, done, GB);
}

// Round 6
// 96.222 us; speedup vs baseline: 1.2430x; 1.2430x over previous
//
#include <hip/hip_runtime.h>
#include <math.h>

// Problem constants (fixed by the harness's setup_inputs()).
#define NN      20000
#define IN_DIM  256
#define HID_DIM 256
#define OUT_DIM 128
#define EE      320000
#define GG      64

#define P_H     8               // partial-histogram blocks per edge array
#define CHUNK   (EE / P_H)      // 40000 edges/block (< 65536 -> u16 safe)
#define NW      10000           // packed words per histogram (2 bins/word)
#define PSTRIDE 10240           // slab stride in words
#define MGB     20              // merge blocks: 20 x 500 words = 10000
#define SB      1250            // scatter blocks: 1250*256 == EE exactly
#define GB      313             // gather blocks: 313*256 >= NN*4

// ---------------------------------------------------------------------------
// Affine collapse (network has no activations):
//   q4 = W4^T lw; q3 = W3^T q4; q2 = W2^T q3; q1 = W1^T q2   (256-vectors)
//   d1 = b1.q2; d2 = b2.q3; d3 = b3.q4; c4 = b4.lw           (scalars)
//   u0 = x.q1;  u_i[c] = sum_{e:col=c} norm_e*(u_{i-1}[row_e] + d_i)
//   out[g] = pool(u4)/maxcnt + lb
//
// Round-15: rocprof showed the real pole was never the q-chain -- it's the
// 640K device-scope histogram atomics, each a ~32B MALL write-through
// (WRITE_SIZE 19.8MB ~= 640K x 32B, at ~450GB/s = ~44us). Fix: LDS-binned
// partial histograms (u16-packed, 40KB/block, zero global atomics) + a
// 20-block merge; the ccnt->scan handoff stays in ONE launch via the proven
// done-counter + MALL-load pattern (scan block spins until merge done).
// Chain single-block (round-4 code, proven). Scatter/gather/final verbatim.
// 8 dispatches: memset, hist∥chain, merge+scan∥cnt∥matvec, scatter, g x3, final.
// ---------------------------------------------------------------------------

__device__ __forceinline__ float ldf_mall(const float* p) {
  return __hip_atomic_load(p, __ATOMIC_RELAXED, __HIP_MEMORY_SCOPE_AGENT);
}
__device__ __forceinline__ int ldi_mall(const int* p) {
  return __hip_atomic_load(p, __ATOMIC_RELAXED, __HIP_MEMORY_SCOPE_AGENT);
}

// D1: blocks [0,16) LDS-binned histogram partials (8 erow, 8 ecol);
// block 16 = full q-chain + bias dots (round-4 code, LDS overlaid).
__global__ __launch_bounds__(1024) void k_hist_chain(
    const int* __restrict__ erow, const int* __restrict__ ecol,
    unsigned int* __restrict__ pdeg, unsigned int* __restrict__ pccnt,
    const float* __restrict__ W1, const float* __restrict__ b1,
    const float* __restrict__ W2, const float* __restrict__ b2,
    const float* __restrict__ W3, const float* __restrict__ b3,
    const float* __restrict__ W4, const float* __restrict__ b4,
    const float* __restrict__ lw, float* __restrict__ q1g,
    float* __restrict__ dv) {
  __shared__ __align__(16) char smem[40960];  // hist 40KB / chain 21KB overlay
  const int bid = blockIdx.x, tid = threadIdx.x;

  if (bid < 2 * P_H) {
    unsigned int* h = (unsigned int*)smem;
    const int  p    = (bid < P_H) ? bid : bid - P_H;
    const int* src  = (bid < P_H) ? erow : ecol;
    unsigned int* slab = ((bid < P_H) ? pdeg : pccnt) + (size_t)p * PSTRIDE;
    for (int w = tid; w < NW; w += 1024) h[w] = 0u;
    __syncthreads();
    const int base = p * CHUNK;
    for (int i = tid; i < CHUNK; i += 1024) {
      int v = src[base + i];
      atomicAdd(&h[v >> 1], 1u << ((v & 1) << 4));   // LDS atomic, packed u16
    }
    __syncthreads();
    for (int w = tid; w < NW; w += 1024) slab[w] = h[w];  // plain coalesced
    return;
  }

  // ---- q-chain block (round-4 proven code; LDS via overlay pointers) ----
  float* fs   = (float*)smem;
  float* lws  = fs;           // 128
  float* qa   = fs + 128;     // q4, 256
  float* qb   = fs + 384;     // q3
  float* qc   = fs + 640;     // q2
  float* qd   = fs + 896;     // q1
  float* part = fs + 1152;    // [16][64][4] = 4096
  float* red  = fs + 5248;    // 16
  const int jj = tid & 63, tq = tid >> 6;

  if (tid < 128) lws[tid] = lw[tid];
  __syncthreads();

  auto gemv = [&](const float* W, const float* qin, float* qout, int K) {
    const int tl = K >> 4, t0 = tq * tl;
    float ax = 0.f, ay = 0.f, az = 0.f, aw = 0.f;
#pragma unroll 8
    for (int t = t0; t < t0 + tl; ++t) {
      const float4 wv = *(const float4*)(W + (size_t)t * 256 + jj * 4);
      const float qv = qin[t];
      ax += wv.x * qv; ay += wv.y * qv; az += wv.z * qv; aw += wv.w * qv;
    }
    part[(tq * 64 + jj) * 4 + 0] = ax; part[(tq * 64 + jj) * 4 + 1] = ay;
    part[(tq * 64 + jj) * 4 + 2] = az; part[(tq * 64 + jj) * 4 + 3] = aw;
    __syncthreads();
    if (tid < 256) {
      float s = 0.f;
#pragma unroll
      for (int k = 0; k < 16; ++k) s += part[(k * 64 + (tid >> 2)) * 4 + (tid & 3)];
      qout[tid] = s;
    }
    __syncthreads();
  };

  gemv(W4, lws, qa, OUT_DIM);   // q4 = W4^T lw   (K = 128)
  gemv(W3, qa, qb, HID_DIM);
  gemv(W2, qb, qc, HID_DIM);
  gemv(W1, qc, qd, HID_DIM);
  if (tid < 256) q1g[tid] = qd[tid];

  auto dot = [&](const float* a, const float* bl, int K, float* dst) {
    float p = (tid < K) ? a[tid] * bl[tid] : 0.f;
#pragma unroll
    for (int off = 32; off; off >>= 1) p += __shfl_down(p, off);
    if ((tid & 63) == 0) red[tid >> 6] = p;
    __syncthreads();
    if (tid == 0) { float s = 0.f; for (int k = 0; k < 16; ++k) s += red[k]; *dst = s; }
    __syncthreads();
  };
  dot(b1, qc, HID_DIM, &dv[0]);
  dot(b2, qb, HID_DIM, &dv[1]);
  dot(b3, qa, HID_DIM, &dv[2]);
  dot(b4, lws, OUT_DIM, &dv[3]);
}

// D2: bid 0 = scan (spins on merge done-counter, reads ccnt via MALL);
// bids [1,20] = merge partials -> deg (plain) + ccnt (atomicAdd, zeroed);
// bid 21 = per-graph node counts; bids 22.. = u0 = x.q1 matvec.
__global__ __launch_bounds__(1024) void k_msc_mv(
    const unsigned int* __restrict__ pdeg, const unsigned int* __restrict__ pccnt,
    int* __restrict__ deg, int* __restrict__ ccnt, int* __restrict__ mergedone,
    int* __restrict__ cstart, int* __restrict__ cursor,
    const int* __restrict__ batch, float* __restrict__ outcnt,
    const float* __restrict__ x, const float* __restrict__ q1,
    float* __restrict__ u0) {
  int bid = blockIdx.x, tid = threadIdx.x, lane = tid & 63, wid = tid >> 6;

  if (bid == 0) {  // exclusive scan of ccnt (verbatim, MALL loads + spin)
    if (tid == 0) {
      while (__hip_atomic_load(mergedone, __ATOMIC_RELAXED, __HIP_MEMORY_SCOPE_AGENT) < MGB)
        __builtin_amdgcn_s_sleep(1);
      (void)__hip_atomic_load(mergedone, __ATOMIC_ACQUIRE, __HIP_MEMORY_SCOPE_AGENT);
    }
    __syncthreads();
    __shared__ int ws[16];
    const int PER = 20;            // 1024*20 = 20480 >= NN
    int base = tid * PER;
    int v[PER]; int sum = 0;
#pragma unroll
    for (int i = 0; i < PER; ++i) {
      int idx = base + i;
      v[i] = (idx < NN) ? ldi_mall(&ccnt[idx]) : 0;
      sum += v[i];
    }
    int incl = sum;
#pragma unroll
    for (int off = 1; off < 64; off <<= 1) { int t = __shfl_up(incl, off); if (lane >= off) incl += t; }
    if (lane == 63) ws[wid] = incl;
    __syncthreads();
    if (tid == 0) { int r = 0; for (int j = 0; j < 16; ++j) { int t = ws[j]; ws[j] = r; r += t; } }
    __syncthreads();
    int run = ws[wid] + incl - sum;
#pragma unroll
    for (int i = 0; i < PER; ++i) {
      int idx = base + i;
      if (idx < NN) { cstart[idx] = run; cursor[idx] = run; }
      run += v[i];
    }
    if (tid == 1023) cstart[NN] = run;   // == EE
    return;
  }

  if (bid <= MGB) {  // merge 8 partials for 500 words (1000 bins)
    int w0 = (bid - 1) * 500;
    for (int w = w0 + tid; w < w0 + 500; w += 1024) {
      unsigned int dlo = 0, dhi = 0, clo = 0, chi = 0;
#pragma unroll
      for (int p = 0; p < P_H; ++p) {
        unsigned int ud = pdeg[(size_t)p * PSTRIDE + w];
        unsigned int uc = pccnt[(size_t)p * PSTRIDE + w];
        dlo += ud & 0xFFFFu; dhi += ud >> 16;
        clo += uc & 0xFFFFu; chi += uc >> 16;
      }
      deg[2 * w] = (int)dlo; deg[2 * w + 1] = (int)dhi;   // next-launch consumer
      atomicAdd(&ccnt[2 * w], (int)clo);                  // same-launch consumer:
      atomicAdd(&ccnt[2 * w + 1], (int)chi);              // write-through RMW
    }
    __syncthreads();
    if (tid == 0)
      __hip_atomic_fetch_add(mergedone, 1, __ATOMIC_RELEASE, __HIP_MEMORY_SCOPE_AGENT);
    return;
  }

  if (bid == MGB + 1) {  // per-graph node counts (verbatim proven code)
    for (int base = 0; base < NN; base += 1024) {
      int n = base + tid;
      int b = -1; float cn = 0.f;
      if (n < NN) { b = batch[n]; cn = 1.f; }
#pragma unroll
      for (int off = 1; off < 64; off <<= 1) {
        float c2 = __shfl_up(cn, off);
        int   b2 = __shfl_up(b, off);
        if (lane >= off && b2 == b) cn += c2;
      }
      int bn = __shfl_down(b, 1);
      if (((lane == 63) || (bn != b)) && b >= 0) atomicAdd(&outcnt[b], cn);
    }
    return;
  }

  // matvec: wave w of block handles row (bid-22)*16 + w.
  int r = (bid - (MGB + 2)) * 16 + wid;
  if (r >= NN) return;
  const float4 xv = *(const float4*)(x + (size_t)r * IN_DIM + lane * 4);
  const float4 qv = *(const float4*)(q1 + lane * 4);
  float s = xv.x * qv.x + xv.y * qv.y + xv.z * qv.z + xv.w * qv.w;
#pragma unroll
  for (int off = 32; off; off >>= 1) s += __shfl_down(s, off);
  if (lane == 0) u0[r] = s;
}

// D3: counting-sort CSR scatter (fused norm), int2-packed {row, val}.
__global__ __launch_bounds__(256) void k_scatter(
    const int* __restrict__ erow, const int* __restrict__ ecol,
    const int* __restrict__ deg, int* __restrict__ cursor,
    int2* __restrict__ sedge) {
  int e = blockIdx.x * 256 + threadIdx.x;   // grid = 1250, exact
  int r = erow[e], c = ecol[e];
  int slot = atomicAdd(&cursor[c], 1);
  float dr = (float)deg[r], dc = (float)deg[c];
  float val = (1.0f / sqrtf(dr)) * (1.0f / sqrtf(dc));  // deg==0 -> inf, as ref
  sedge[slot] = make_int2(r, __float_as_int(val));
}

// D4-D6: atomic-free A-application, 4 lanes per node (proven verbatim).
__global__ __launch_bounds__(256) void k_gather(
    const int* __restrict__ cstart, const int2* __restrict__ sedge,
    const float* __restrict__ uin, const float* __restrict__ dptr,
    float* __restrict__ uout) {
  int gid = blockIdx.x * 256 + threadIdx.x;
  int n = gid >> 2, l = gid & 3;
  if (n >= NN) return;
  int s0 = cstart[n], s1 = cstart[n + 1];
  float acc = 0.f, es = 0.f;
  for (int s = s0 + l; s < s1; s += 4) {
    int2 ev = sedge[s];
    float v = __int_as_float(ev.y);
    acc += v * uin[ev.x];
    es  += v;
  }
  acc += __shfl_xor(acc, 1); es += __shfl_xor(es, 1);
  acc += __shfl_xor(acc, 2); es += __shfl_xor(es, 2);
  if (l == 0) uout[n] = acc + dptr[0] * es;
}

// D7: last A-application + segmented per-node pool + last-block finalize.
__global__ __launch_bounds__(256) void k_gather_pool_final(
    const int* __restrict__ cstart, const int2* __restrict__ sedge,
    const float* __restrict__ uin, const float* __restrict__ dptr,
    const int* __restrict__ batch, float* __restrict__ outsum,
    const float* __restrict__ outcnt, const float* __restrict__ lb,
    float* __restrict__ out, int* __restrict__ done, int nblocks) {
  int gid = blockIdx.x * 256 + threadIdx.x;
  int lane = threadIdx.x & 63;
  int n = gid >> 2, l = gid & 3;
  float pv = 0.f; int b = -1;
  if (n < NN) {
    int s0 = cstart[n], s1 = cstart[n + 1];
    float acc = 0.f, es = 0.f;
    for (int s = s0 + l; s < s1; s += 4) {
      int2 ev = sedge[s];
      float v = __int_as_float(ev.y);
      acc += v * uin[ev.x];
      es  += v;
    }
    acc += __shfl_xor(acc, 1); es += __shfl_xor(es, 1);
    acc += __shfl_xor(acc, 2); es += __shfl_xor(es, 2);
    b = batch[n];
    if (l == 0) pv = acc + dptr[0] * es;   // node total on lane l==0 only
  }
#pragma unroll
  for (int off = 1; off < 64; off <<= 1) {
    float s2 = __shfl_up(pv, off);
    int   b2 = __shfl_up(b, off);
    if (lane >= off && b2 == b) pv += s2;
  }
  int bn = __shfl_down(b, 1);
  if (((lane == 63) || (bn != b)) && b >= 0) atomicAdd(&outsum[b], pv);

  // __syncthreads drains this block's vmem (outsum atomics complete at MALL)
  // before thread 0 signals; the LAST block to signal finalizes, reading
  // outsum/outcnt through MALL-coherent loads (proven pattern).
  __syncthreads();
  __shared__ int winner;
  if (threadIdx.x == 0) {
    int old = __hip_atomic_fetch_add(done, 1, __ATOMIC_RELAXED, __HIP_MEMORY_SCOPE_AGENT);
    winner = (old == nblocks - 1) ? 1 : 0;
  }
  __syncthreads();
  if (winner && threadIdx.x < GG) {
    int g = threadIdx.x;
    float m = ldf_mall(&outcnt[g]);
#pragma unroll
    for (int off = 32; off; off >>= 1) m = fmaxf(m, __shfl_xor(m, off));
    out[g] = ldf_mall(&outsum[g]) / m + lb[0];
  }
}

extern "C" void kernel_launch(void* const* d_in, const int* in_sizes, int n_in,
                              void* d_out, int out_size, void* d_ws, size_t ws_size,
                              hipStream_t stream) {
  (void)in_sizes; (void)n_in; (void)out_size; (void)ws_size;
  const float* x     = (const float*)d_in[0];
  const int*   erow  = (const int*)d_in[1];          // edge_index[0,:]
  const int*   ecol  = ((const int*)d_in[1]) + EE;   // edge_index[1,:]
  const int*   batch = (const int*)d_in[2];
  const float* W1 = (const float*)d_in[4];
  const float* b1 = (const float*)d_in[5];
  const float* W2 = (const float*)d_in[6];
  const float* b2 = (const float*)d_in[7];
  const float* W3 = (const float*)d_in[8];
  const float* b3 = (const float*)d_in[9];
  const float* W4 = (const float*)d_in[10];
  const float* b4 = (const float*)d_in[11];
  const float* lw = (const float*)d_in[12];
  const float* lb = (const float*)d_in[13];
  float* out = (float*)d_out;

  // Workspace layout (256-byte aligned slots).
  const size_t PN = 80128;  // 20000*4 rounded up to 256
  char* w = (char*)d_ws;
  // --- memset zone ---
  int*   ccnt      = (int*)w;    w += PN;   // merge atomicAdd target
  float* outsum    = (float*)w;  w += 256;
  float* outcnt    = (float*)w;  w += 256;
  int*   done      = (int*)w;    w += 256;
  int*   mergedone = (int*)w;    w += 256;
  size_t zbytes = (size_t)(w - (char*)d_ws);
  // --- fully-overwritten scratch ---
  int*   deg    = (int*)w;    w += PN;
  int*   cstart = (int*)w;    w += PN + 256;          // NN+1 entries
  int*   cursor = (int*)w;    w += PN;
  int2*  sedge  = (int2*)w;   w += (size_t)EE * 8;    // packed {row, norm}
  unsigned int* pdeg  = (unsigned int*)w; w += (size_t)P_H * PSTRIDE * 4;
  unsigned int* pccnt = (unsigned int*)w; w += (size_t)P_H * PSTRIDE * 4;
  float* q1     = (float*)w;  w += 1024;
  float* dv     = (float*)w;  w += 256;
  float* u0     = (float*)w;  w += PN;
  float* u1     = (float*)w;  w += PN;
  float* u2     = (float*)w;  w += PN;
  float* u3     = (float*)w;  w += PN;

  // D0: zero accumulators (stream-ordered, graph-capture-safe).
  hipMemsetAsync(d_ws, 0, zbytes, stream);
  // D1: LDS-binned histogram partials ∥ q-chain + bias dots.
  k_hist_chain<<<2 * P_H + 1, 1024, 0, stream>>>(erow, ecol, pdeg, pccnt,
                                                 W1, b1, W2, b2, W3, b3, W4, b4,
                                                 lw, q1, dv);
  // D2: merge + scan (done-counter) ∥ graph counts ∥ u0 = x.q1.
  k_msc_mv<<<MGB + 2 + 1250, 1024, 0, stream>>>(pdeg, pccnt, deg, ccnt, mergedone,
                                                cstart, cursor, batch, outcnt,
                                                x, q1, u0);
  // D3: CSR counting-sort scatter.
  k_scatter<<<SB, 256, 0, stream>>>(erow, ecol, deg, cursor, sedge);
  // D4-D6: three A-applications.
  k_gather<<<GB, 256, 0, stream>>>(cstart, sedge, u0, dv + 0, u1);
  k_gather<<<GB, 256, 0, stream>>>(cstart, sedge, u1, dv + 1, u2);
  k_gather<<<GB, 256, 0, stream>>>(cstart, sedge, u2, dv + 2, u3);
  // D7: last application + per-node pool + last-block finalize.
  k_gather_pool_final<<<GB, 256, 0, stream>>>(cstart, sedge, u3, dv + 3, batch,
                                              outsum, outcnt, lb, out, done, GB);
}

// Round 7
// 82.411 us; speedup vs baseline: 1.4513x; 1.1676x over previous
//
#include <hip/hip_runtime.h>
#include <math.h>

// Problem constants (fixed by the harness's setup_inputs()).
#define NN      20000
#define IN_DIM  256
#define HID_DIM 256
#define OUT_DIM 128
#define EE      320000
#define GG      64

#define P_H     8               // partial-histogram blocks per edge array
#define CHUNK   (EE / P_H)      // 40000 edges/block (< 65536 -> u16 safe)
#define NW      10000           // packed words per histogram (2 bins/word)
#define PSTRIDE 10240           // slab stride in words
#define CHB     16              // cooperative q-chain blocks
#define MGB     20              // merge blocks: 20 x 500 words = 10000
#define SB      1250            // scatter blocks: 1250*256 == EE exactly
#define GB      313             // gather blocks: 313*256 >= NN*4

// ---------------------------------------------------------------------------
// Affine collapse (network has no activations):
//   q4 = W4^T lw; q3 = W3^T q4; q2 = W2^T q3; q1 = W1^T q2   (256-vectors)
//   d1 = b1.q2; d2 = b2.q3; d3 = b3.q4; c4 = b4.lw           (scalars)
//   u0 = x.q1;  u_i[c] = sum_{e:col=c} norm_e*(u_{i-1}[row_e] + d_i)
//   out[g] = pool(u4)/maxcnt + lb
//
// Round-16: round-15 killed the histogram atomics (96us). Remaining poles:
// (a) single-block q-chain = one CU streaming 900KB W at ~30GB/s (~30us);
// (b) scatter's 320K cursor atomics (~10MB MALL write-through, ~12us).
// Fixes: (a) chain -> 16 cooperative blocks, output-split per stage, chained
// by the PROVEN done-counter (release-add / relaxed-poll / MALL-load)
// pattern; (b) atomic-free scatter: LDS-histogram atomicAdd RETURN VALUE is
// a chunk-local rank (stored u16); merge emits per-column chunk prefix
// offsets; slot = cstart[c] + chunkoff[c][p] + rank[e]. cursor + all global
// scatter atomics deleted; ccnt now plain-stored by merge.
// 8 dispatches: memset(1.3KB), hist∥chain, merge+scan∥cnt∥matvec, scatter,
// gather x3, gather+pool+finalize.
// ---------------------------------------------------------------------------

__device__ __forceinline__ float ldf_mall(const float* p) {
  return __hip_atomic_load(p, __ATOMIC_RELAXED, __HIP_MEMORY_SCOPE_AGENT);
}
__device__ __forceinline__ int ldi_mall(const int* p) {
  return __hip_atomic_load(p, __ATOMIC_RELAXED, __HIP_MEMORY_SCOPE_AGENT);
}

// D1: blocks [0,16) LDS-binned histogram partials (8 erow, 8 ecol+ranks);
// blocks [16,32) cooperative q-chain (output-split, done-counter chained).
__global__ __launch_bounds__(1024) void k_hist_chain(
    const int* __restrict__ erow, const int* __restrict__ ecol,
    unsigned int* __restrict__ pdeg, unsigned int* __restrict__ pccnt,
    unsigned short* __restrict__ rankb,
    const float* __restrict__ W1, const float* __restrict__ b1,
    const float* __restrict__ W2, const float* __restrict__ b2,
    const float* __restrict__ W3, const float* __restrict__ b3,
    const float* __restrict__ W4, const float* __restrict__ b4,
    const float* __restrict__ lw,
    float* __restrict__ q4g, float* __restrict__ q3g,
    float* __restrict__ q2g, float* __restrict__ q1g,
    float* __restrict__ dv, int* __restrict__ chaindone) {
  __shared__ __align__(16) char smem[40960];
  const int bid = blockIdx.x, tid = threadIdx.x;

  if (bid < 2 * P_H) {
    unsigned int* h = (unsigned int*)smem;
    const int  p   = bid & (P_H - 1);
    const bool isc = bid >= P_H;
    const int* src = isc ? ecol : erow;
    unsigned int* slab = (isc ? pccnt : pdeg) + (size_t)p * PSTRIDE;
    for (int w = tid; w < NW; w += 1024) h[w] = 0u;
    __syncthreads();
    const int base = p * CHUNK;
    for (int i = tid; i < CHUNK; i += 1024) {
      int v = src[base + i];
      int sh = (v & 1) << 4;
      unsigned int old = atomicAdd(&h[v >> 1], 1u << sh);  // LDS, packed u16
      if (isc) rankb[base + i] = (unsigned short)((old >> sh) & 0xFFFFu);
    }
    __syncthreads();
    for (int w = tid; w < NW; w += 1024) slab[w] = h[w];   // plain coalesced
    return;
  }

  // ---- cooperative q-chain: block cb owns outputs [16cb, 16cb+16) ----
  const int cb = bid - 2 * P_H;
  float* fs  = (float*)smem;
  float* lwl = fs;            // 128   (lw staged; survives for b4 dot)
  float* qs4 = fs + 128;      // 256   q4 (staged at stage 2)
  float* qs3 = fs + 384;      // 256   q3 (staged at stage 3)
  float* qs2 = fs + 640;      // 256   q2 (staged at stage 4)
  float* part = fs + 896;     // [64][16] = 1024
  float* red  = fs + 1920;    // 16
  const int jj = tid & 15, tt = tid >> 4;    // tt in [0,64)
  const int jg = cb * 16 + jj;

  if (tid < 128) lwl[tid] = lw[tid];
  __syncthreads();

  // Arrive at the stage fence, then wait until all CHB blocks arrived.
  auto arrive_wait = [&](int target) {
    __syncthreads();   // drains this block's vmem before the release
    if (tid == 0) {
      __hip_atomic_fetch_add(chaindone, 1, __ATOMIC_RELEASE, __HIP_MEMORY_SCOPE_AGENT);
      while (__hip_atomic_load(chaindone, __ATOMIC_RELAXED, __HIP_MEMORY_SCOPE_AGENT) < target)
        __builtin_amdgcn_s_sleep(1);
      (void)__hip_atomic_load(chaindone, __ATOMIC_ACQUIRE, __HIP_MEMORY_SCOPE_AGENT);
    }
    __syncthreads();
  };
  // One gemv stage: qout[jg] = sum_t W[t*256+jg] * qin[t], 16 outputs/block.
  auto stage = [&](const float* W, const float* qin, int K, float* qout_g) {
    float acc = 0.f;
    for (int t = tt; t < K; t += 64) acc += W[(size_t)t * 256 + jg] * qin[t];
    part[tt * 16 + jj] = acc;
    __syncthreads();
    if (tid < 16) {
      float s = 0.f;
#pragma unroll
      for (int k = 0; k < 64; ++k) s += part[k * 16 + tid];
      qout_g[cb * 16 + tid] = s;
    }
  };
  auto load_q = [&](const float* qg, float* qdst) {
    if (tid < 256) qdst[tid] = ldf_mall(qg + tid);
    __syncthreads();
  };

  stage(W4, lwl, OUT_DIM, q4g);  arrive_wait(1 * CHB);
  load_q(q4g, qs4);
  stage(W3, qs4, HID_DIM, q3g);  arrive_wait(2 * CHB);
  load_q(q3g, qs3);
  stage(W2, qs3, HID_DIM, q2g);  arrive_wait(3 * CHB);
  load_q(q2g, qs2);
  stage(W1, qs2, HID_DIM, q1g);  // q1/dv consumed next launch: no fence

  if (cb == 0) {
    __syncthreads();
    auto dot = [&](const float* a, const float* bl, int K, float* dst) {
      float p = (tid < K) ? a[tid] * bl[tid] : 0.f;
#pragma unroll
      for (int off = 32; off; off >>= 1) p += __shfl_down(p, off);
      if ((tid & 63) == 0) red[tid >> 6] = p;
      __syncthreads();
      if (tid == 0) { float s = 0.f; for (int k = 0; k < 16; ++k) s += red[k]; *dst = s; }
      __syncthreads();
    };
    dot(b1, qs2, HID_DIM, &dv[0]);
    dot(b2, qs3, HID_DIM, &dv[1]);
    dot(b3, qs4, HID_DIM, &dv[2]);
    dot(b4, lwl, OUT_DIM, &dv[3]);
  }
}

// D2: bid 0 = scan (spins on merge done-counter, reads ccnt via MALL);
// bids [1,20] = merge partials -> deg/ccnt (plain) + chunkoff prefixes;
// bid 21 = per-graph node counts; bids 22.. = u0 = x.q1 matvec.
__global__ __launch_bounds__(1024) void k_msc_mv(
    const unsigned int* __restrict__ pdeg, const unsigned int* __restrict__ pccnt,
    int* __restrict__ deg, int* __restrict__ ccnt,
    unsigned short* __restrict__ chunkoff, int* __restrict__ mergedone,
    int* __restrict__ cstart,
    const int* __restrict__ batch, float* __restrict__ outcnt,
    const float* __restrict__ x, const float* __restrict__ q1,
    float* __restrict__ u0) {
  int bid = blockIdx.x, tid = threadIdx.x, lane = tid & 63, wid = tid >> 6;

  if (bid == 0) {  // exclusive scan of ccnt (spin on merge, MALL loads)
    if (tid == 0) {
      while (__hip_atomic_load(mergedone, __ATOMIC_RELAXED, __HIP_MEMORY_SCOPE_AGENT) < MGB)
        __builtin_amdgcn_s_sleep(1);
      (void)__hip_atomic_load(mergedone, __ATOMIC_ACQUIRE, __HIP_MEMORY_SCOPE_AGENT);
    }
    __syncthreads();
    __shared__ int ws[16];
    const int PER = 20;            // 1024*20 = 20480 >= NN
    int base = tid * PER;
    int v[PER]; int sum = 0;
#pragma unroll
    for (int i = 0; i < PER; ++i) {
      int idx = base + i;
      v[i] = (idx < NN) ? ldi_mall(&ccnt[idx]) : 0;
      sum += v[i];
    }
    int incl = sum;
#pragma unroll
    for (int off = 1; off < 64; off <<= 1) { int t = __shfl_up(incl, off); if (lane >= off) incl += t; }
    if (lane == 63) ws[wid] = incl;
    __syncthreads();
    if (tid == 0) { int r = 0; for (int j = 0; j < 16; ++j) { int t = ws[j]; ws[j] = r; r += t; } }
    __syncthreads();
    int run = ws[wid] + incl - sum;
#pragma unroll
    for (int i = 0; i < PER; ++i) {
      int idx = base + i;
      if (idx < NN) cstart[idx] = run;
      run += v[i];
    }
    if (tid == 1023) cstart[NN] = run;   // == EE
    return;
  }

  if (bid <= MGB) {  // merge 8 partials for 500 words (1000 bins) + prefixes
    int w0 = (bid - 1) * 500;
    for (int w = w0 + tid; w < w0 + 500; w += 1024) {
      unsigned int dlo = 0, dhi = 0, clo = 0, chi = 0;
      const int c0 = 2 * w, c1 = 2 * w + 1;
#pragma unroll
      for (int p = 0; p < P_H; ++p) {
        unsigned int ud = pdeg[(size_t)p * PSTRIDE + w];
        unsigned int uc = pccnt[(size_t)p * PSTRIDE + w];
        dlo += ud & 0xFFFFu; dhi += ud >> 16;
        chunkoff[(size_t)c0 * P_H + p] = (unsigned short)clo;  // exclusive
        chunkoff[(size_t)c1 * P_H + p] = (unsigned short)chi;
        clo += uc & 0xFFFFu; chi += uc >> 16;
      }
      deg[c0]  = (int)dlo; deg[c1]  = (int)dhi;   // next-launch consumers:
      ccnt[c0] = (int)clo; ccnt[c1] = (int)chi;   // plain stores + release
    }
    __syncthreads();
    if (tid == 0)
      __hip_atomic_fetch_add(mergedone, 1, __ATOMIC_RELEASE, __HIP_MEMORY_SCOPE_AGENT);
    return;
  }

  if (bid == MGB + 1) {  // per-graph node counts (verbatim proven code)
    for (int base = 0; base < NN; base += 1024) {
      int n = base + tid;
      int b = -1; float cn = 0.f;
      if (n < NN) { b = batch[n]; cn = 1.f; }
#pragma unroll
      for (int off = 1; off < 64; off <<= 1) {
        float c2 = __shfl_up(cn, off);
        int   b2 = __shfl_up(b, off);
        if (lane >= off && b2 == b) cn += c2;
      }
      int bn = __shfl_down(b, 1);
      if (((lane == 63) || (bn != b)) && b >= 0) atomicAdd(&outcnt[b], cn);
    }
    return;
  }

  // matvec: wave w of block handles row (bid-22)*16 + w.
  int r = (bid - (MGB + 2)) * 16 + wid;
  if (r >= NN) return;
  const float4 xv = *(const float4*)(x + (size_t)r * IN_DIM + lane * 4);
  const float4 qv = *(const float4*)(q1 + lane * 4);
  float s = xv.x * qv.x + xv.y * qv.y + xv.z * qv.z + xv.w * qv.w;
#pragma unroll
  for (int off = 32; off; off >>= 1) s += __shfl_down(s, off);
  if (lane == 0) u0[r] = s;
}

// D3: atomic-free CSR scatter: slot = cstart[c] + chunkoff[c][p] + rank[e].
__global__ __launch_bounds__(256) void k_scatter(
    const int* __restrict__ erow, const int* __restrict__ ecol,
    const int* __restrict__ deg, const int* __restrict__ cstart,
    const unsigned short* __restrict__ chunkoff,
    const unsigned short* __restrict__ rankb,
    int2* __restrict__ sedge) {
  int e = blockIdx.x * 256 + threadIdx.x;   // grid = 1250, exact
  int r = erow[e], c = ecol[e];
  int p = e / CHUNK;
  int slot = cstart[c] + (int)chunkoff[(size_t)c * P_H + p] + (int)rankb[e];
  float dr = (float)deg[r], dc = (float)deg[c];
  float val = (1.0f / sqrtf(dr)) * (1.0f / sqrtf(dc));  // deg==0 -> inf, as ref
  sedge[slot] = make_int2(r, __float_as_int(val));
}

// D4-D6: atomic-free A-application, 4 lanes per node (proven verbatim).
__global__ __launch_bounds__(256) void k_gather(
    const int* __restrict__ cstart, const int2* __restrict__ sedge,
    const float* __restrict__ uin, const float* __restrict__ dptr,
    float* __restrict__ uout) {
  int gid = blockIdx.x * 256 + threadIdx.x;
  int n = gid >> 2, l = gid & 3;
  if (n >= NN) return;
  int s0 = cstart[n], s1 = cstart[n + 1];
  float acc = 0.f, es = 0.f;
  for (int s = s0 + l; s < s1; s += 4) {
    int2 ev = sedge[s];
    float v = __int_as_float(ev.y);
    acc += v * uin[ev.x];
    es  += v;
  }
  acc += __shfl_xor(acc, 1); es += __shfl_xor(es, 1);
  acc += __shfl_xor(acc, 2); es += __shfl_xor(es, 2);
  if (l == 0) uout[n] = acc + dptr[0] * es;
}

// D7: last A-application + segmented per-node pool + last-block finalize.
__global__ __launch_bounds__(256) void k_gather_pool_final(
    const int* __restrict__ cstart, const int2* __restrict__ sedge,
    const float* __restrict__ uin, const float* __restrict__ dptr,
    const int* __restrict__ batch, float* __restrict__ outsum,
    const float* __restrict__ outcnt, const float* __restrict__ lb,
    float* __restrict__ out, int* __restrict__ done, int nblocks) {
  int gid = blockIdx.x * 256 + threadIdx.x;
  int lane = threadIdx.x & 63;
  int n = gid >> 2, l = gid & 3;
  float pv = 0.f; int b = -1;
  if (n < NN) {
    int s0 = cstart[n], s1 = cstart[n + 1];
    float acc = 0.f, es = 0.f;
    for (int s = s0 + l; s < s1; s += 4) {
      int2 ev = sedge[s];
      float v = __int_as_float(ev.y);
      acc += v * uin[ev.x];
      es  += v;
    }
    acc += __shfl_xor(acc, 1); es += __shfl_xor(es, 1);
    acc += __shfl_xor(acc, 2); es += __shfl_xor(es, 2);
    b = batch[n];
    if (l == 0) pv = acc + dptr[0] * es;   // node total on lane l==0 only
  }
#pragma unroll
  for (int off = 1; off < 64; off <<= 1) {
    float s2 = __shfl_up(pv, off);
    int   b2 = __shfl_up(b, off);
    if (lane >= off && b2 == b) pv += s2;
  }
  int bn = __shfl_down(b, 1);
  if (((lane == 63) || (bn != b)) && b >= 0) atomicAdd(&outsum[b], pv);

  // __syncthreads drains this block's vmem (outsum atomics complete at MALL)
  // before thread 0 signals; the LAST block to signal finalizes, reading
  // outsum/outcnt through MALL-coherent loads (proven pattern).
  __syncthreads();
  __shared__ int winner;
  if (threadIdx.x == 0) {
    int old = __hip_atomic_fetch_add(done, 1, __ATOMIC_RELAXED, __HIP_MEMORY_SCOPE_AGENT);
    winner = (old == nblocks - 1) ? 1 : 0;
  }
  __syncthreads();
  if (winner && threadIdx.x < GG) {
    int g = threadIdx.x;
    float m = ldf_mall(&outcnt[g]);
#pragma unroll
    for (int off = 32; off; off >>= 1) m = fmaxf(m, __shfl_xor(m, off));
    out[g] = ldf_mall(&outsum[g]) / m + lb[0];
  }
}

extern "C" void kernel_launch(void* const* d_in, const int* in_sizes, int n_in,
                              void* d_out, int out_size, void* d_ws, size_t ws_size,
                              hipStream_t stream) {
  (void)in_sizes; (void)n_in; (void)out_size; (void)ws_size;
  const float* x     = (const float*)d_in[0];
  const int*   erow  = (const int*)d_in[1];          // edge_index[0,:]
  const int*   ecol  = ((const int*)d_in[1]) + EE;   // edge_index[1,:]
  const int*   batch = (const int*)d_in[2];
  const float* W1 = (const float*)d_in[4];
  const float* b1 = (const float*)d_in[5];
  const float* W2 = (const float*)d_in[6];
  const float* b2 = (const float*)d_in[7];
  const float* W3 = (const float*)d_in[8];
  const float* b3 = (const float*)d_in[9];
  const float* W4 = (const float*)d_in[10];
  const float* b4 = (const float*)d_in[11];
  const float* lw = (const float*)d_in[12];
  const float* lb = (const float*)d_in[13];
  float* out = (float*)d_out;

  // Workspace layout (256-byte aligned slots).
  const size_t PN = 80128;  // 20000*4 rounded up to 256
  char* w = (char*)d_ws;
  // --- memset zone (1.3KB) ---
  float* outsum    = (float*)w;  w += 256;
  float* outcnt    = (float*)w;  w += 256;
  int*   done      = (int*)w;    w += 256;
  int*   mergedone = (int*)w;    w += 256;
  int*   chaindone = (int*)w;    w += 256;
  size_t zbytes = (size_t)(w - (char*)d_ws);
  // --- fully-overwritten scratch ---
  int*   deg    = (int*)w;    w += PN;
  int*   ccnt   = (int*)w;    w += PN;
  int*   cstart = (int*)w;    w += PN + 256;          // NN+1 entries
  int2*  sedge  = (int2*)w;   w += (size_t)EE * 8;    // packed {row, norm}
  unsigned int*   pdeg  = (unsigned int*)w;   w += (size_t)P_H * PSTRIDE * 4;
  unsigned int*   pccnt = (unsigned int*)w;   w += (size_t)P_H * PSTRIDE * 4;
  unsigned short* chunkoff = (unsigned short*)w; w += (size_t)NN * P_H * 2;
  unsigned short* rankb    = (unsigned short*)w; w += (size_t)EE * 2;
  float* q4 = (float*)w;  w += 1024;
  float* q3 = (float*)w;  w += 1024;
  float* q2 = (float*)w;  w += 1024;
  float* q1 = (float*)w;  w += 1024;
  float* dv = (float*)w;  w += 256;
  float* u0 = (float*)w;  w += PN;
  float* u1 = (float*)w;  w += PN;
  float* u2 = (float*)w;  w += PN;
  float* u3 = (float*)w;  w += PN;

  // D0: zero the tiny counter zone (stream-ordered, graph-capture-safe).
  hipMemsetAsync(d_ws, 0, zbytes, stream);
  // D1: LDS-binned histogram partials (+ranks) ∥ cooperative q-chain.
  k_hist_chain<<<2 * P_H + CHB, 1024, 0, stream>>>(erow, ecol, pdeg, pccnt, rankb,
                                                   W1, b1, W2, b2, W3, b3, W4, b4,
                                                   lw, q4, q3, q2, q1, dv, chaindone);
  // D2: merge + scan (done-counter) ∥ graph counts ∥ u0 = x.q1.
  k_msc_mv<<<MGB + 2 + 1250, 1024, 0, stream>>>(pdeg, pccnt, deg, ccnt, chunkoff,
                                                mergedone, cstart, batch, outcnt,
                                                x, q1, u0);
  // D3: atomic-free CSR scatter.
  k_scatter<<<SB, 256, 0, stream>>>(erow, ecol, deg, cstart, chunkoff, rankb, sedge);
  // D4-D6: three A-applications.
  k_gather<<<GB, 256, 0, stream>>>(cstart, sedge, u0, dv + 0, u1);
  k_gather<<<GB, 256, 0, stream>>>(cstart, sedge, u1, dv + 1, u2);
  k_gather<<<GB, 256, 0, stream>>>(cstart, sedge, u2, dv + 2, u3);
  // D7: last application + per-node pool + last-block finalize.
  k_gather_pool_final<<<GB, 256, 0, stream>>>(cstart, sedge, u3, dv + 3, batch,
                                              outsum, outcnt, lb, out, done, GB);
}